// Round 7
// baseline (14020.999 us; speedup 1.0000x reference)
//
#include <hip/hip_runtime.h>
#include <hip/hip_cooperative_groups.h>

namespace cg = cooperative_groups;

#define LN_EPS 1e-3f

typedef short s8v __attribute__((ext_vector_type(8)));
typedef float f4v __attribute__((ext_vector_type(4)));
typedef unsigned short u16;

#define MFMA16 __builtin_amdgcn_mfma_f32_16x16x32_bf16

__device__ __forceinline__ u16 f2bf(float f) {
  unsigned int x = __float_as_uint(f);
  x += 0x7fffu + ((x >> 16) & 1u);
  return (u16)(x >> 16);
}
__device__ __forceinline__ float bf2f(u16 u) {
  return __uint_as_float(((unsigned int)u) << 16);
}

__device__ __forceinline__ void glds16(const u16* g, void* l) {
  __builtin_amdgcn_global_load_lds(
      (const __attribute__((address_space(1))) void*)g,
      (__attribute__((address_space(3))) void*)l, 16, 0, 0);
}

#define RAW_BAR() do { __builtin_amdgcn_s_barrier(); __builtin_amdgcn_sched_barrier(0); } while (0)

// ---------------- fp32 -> bf16 conversion ----------------
__global__ void k_cvt(const float* __restrict__ src, u16* __restrict__ dst, int n) {
  int i = blockIdx.x * blockDim.x + threadIdx.x;
  int stride = gridDim.x * blockDim.x;
  for (; i < n; i += stride) dst[i] = f2bf(src[i]);
}

// pack GRU weights: wt[nt(32)][s(48)][sub(3)][ch(8)][row(64)][8]
__global__ void k_packgru(const float* __restrict__ wih,
                          const float* __restrict__ whh, u16* __restrict__ wt) {
  int u = blockIdx.x * 256 + threadIdx.x;  // 16B units, total 2359296
  int nt = u / 73728;
  int r1 = u % 73728;
  int s = r1 / 1536;
  int r2 = r1 % 1536;
  int sub = r2 / 512;
  int r3 = r2 % 512;
  int ch = r3 / 64;
  int row = r3 % 64;
  int j = nt * 64 + row;
  int kbase = s * 64 + ch * 8;
  s8v v;
#pragma unroll
  for (int e = 0; e < 8; ++e) {
    int kk = kbase + e;
    float x;
    if (sub == 0) {
      x = kk < 1024 ? wih[(size_t)j * 1024 + kk] : whh[(size_t)j * 2048 + kk - 1024];
    } else if (sub == 1) {
      int jj = 2048 + j;
      x = kk < 1024 ? wih[(size_t)jj * 1024 + kk] : whh[(size_t)jj * 2048 + kk - 1024];
    } else {
      int jj = 4096 + j;
      x = (s < 16) ? wih[(size_t)jj * 1024 + kk] : whh[(size_t)jj * 2048 + kk - 1024];
    }
    v[e] = (short)f2bf(x);
  }
  *(s8v*)(wt + (size_t)u * 8) = v;
}

// generic chunk-linear pack: dst[nt][s][ch(8)][row(BN)][8] from src[N][K] f32
__global__ void k_packB(const float* __restrict__ src, u16* __restrict__ dst,
                        int K, int BN, int total) {
  int u = blockIdx.x * 256 + threadIdx.x;
  if (u >= total) return;
  int ns = K >> 6;
  int perNt = ns * 8 * BN;
  int nt = u / perNt;
  int r1 = u % perNt;
  int s = r1 / (8 * BN);
  int r2 = r1 % (8 * BN);
  int ch = r2 / BN;
  int row = r2 % BN;
  int j = nt * BN + row;
  int k = s * 64 + ch * 8;
  const float* sp = src + (size_t)j * K + k;
  s8v v;
#pragma unroll
  for (int e = 0; e < 8; ++e) v[e] = (short)f2bf(sp[e]);
  *(s8v*)(dst + (size_t)u * 8) = v;
}

// awT[k*512+c] = aw[c*10+k]
__global__ void k_trA(const float* __restrict__ aw, float* __restrict__ awT) {
  int i = blockIdx.x * 256 + threadIdx.x;
  if (i >= 5120) return;
  int k = i >> 9, c = i & 511;
  awT[i] = aw[c * 10 + k];
}

// h0 -> hf (f32) and hcat (bf16)
__global__ void k_hinit(const float* __restrict__ h0, float* __restrict__ hf,
                        u16* __restrict__ hcat) {
  int i = blockIdx.x * 256 + threadIdx.x;  // 524288
  float v = h0[i];
  hf[i] = v;
  hcat[i] = f2bf(v);
}

// ---------------- t=0 za: elu(LN(concat(z@zw^T+zb, a@aw^T))) ----------------
__global__ __launch_bounds__(256) void k_za0(
    const float* __restrict__ zsrc, const float* __restrict__ act,
    const float* __restrict__ zw, const float* __restrict__ zb,
    const float* __restrict__ aw, const float* __restrict__ lns,
    const float* __restrict__ lnb, u16* __restrict__ za) {
  const int b = blockIdx.x, tid = threadIdx.x;
  __shared__ float zsh[64];
  __shared__ float ash[12];
  __shared__ float wred[8];
  if (tid < 64) zsh[tid] = zsrc[b * 64 + tid];
  if (tid < 10) ash[tid] = act[b * 10 + tid];
  __syncthreads();
  float x[4];
#pragma unroll
  for (int i = 0; i < 2; ++i) {
    int c = tid + i * 256;
    const float4* wp = (const float4*)(zw + c * 64);
    float a = zb[c];
#pragma unroll
    for (int k = 0; k < 16; ++k) {
      float4 v = wp[k];
      a += zsh[k * 4] * v.x + zsh[k * 4 + 1] * v.y + zsh[k * 4 + 2] * v.z +
           zsh[k * 4 + 3] * v.w;
    }
    x[i] = a;
  }
#pragma unroll
  for (int i = 2; i < 4; ++i) {
    int c2 = tid + (i - 2) * 256;
    const float* wp = aw + c2 * 10;
    float a = 0.f;
#pragma unroll
    for (int k = 0; k < 10; ++k) a += ash[k] * wp[k];
    x[i] = a;
  }
  float s = x[0] + x[1] + x[2] + x[3];
#pragma unroll
  for (int o = 1; o < 64; o <<= 1) s += __shfl_xor(s, o);
  if ((tid & 63) == 0) wred[tid >> 6] = s;
  __syncthreads();
  float mu = (wred[0] + wred[1] + wred[2] + wred[3]) * (1.f / 1024.f);
  float q = 0.f;
#pragma unroll
  for (int i = 0; i < 4; ++i) {
    float d = x[i] - mu;
    q += d * d;
  }
#pragma unroll
  for (int o = 1; o < 64; o <<= 1) q += __shfl_xor(q, o);
  if ((tid & 63) == 0) wred[4 + (tid >> 6)] = q;
  __syncthreads();
  float rs = rsqrtf((wred[4] + wred[5] + wred[6] + wred[7]) * (1.f / 1024.f) + LN_EPS);
  int cols[4] = {tid, tid + 256, 512 + tid, 768 + tid};
#pragma unroll
  for (int i = 0; i < 4; ++i) {
    int c = cols[i];
    float y = (x[i] - mu) * rs * lns[c] + lnb[c];
    y = y > 0.f ? y : expm1f(y);
    za[(size_t)b * 1024 + c] = f2bf(y);
  }
}

// ---------------- persistent cooperative scan kernel ----------------
struct ScanArgs {
  const u16* wt;
  const float* bih;
  const float* bhh;
  u16* hcat0;
  u16* hcat1;
  float* hf0;
  float* hf1;
  u16* za;
  const u16* posthP;
  const float* post_h_b;
  const u16* e_part;
  float* xbuf;
  const u16* postwP;
  const float* ln_post_s;
  const float* ln_post_b;
  const float* post_b;
  float* out_posts;
  const float* noise;
  float* out_z;
  float* out_feat;
  const u16* zwP;
  const float* z_mlp_b;
  const float* awT;
  const float* actions;
  const float* ln_za_s;
  const float* ln_za_b;
};

__global__ __launch_bounds__(512) void k_scan(ScanArgs a) {
  cg::grid_group grid = cg::this_grid();
  const int bid = blockIdx.x;
  const int tid = threadIdx.x;
  const int lane = tid & 63;
  const int w = tid >> 6;  // 0..7
  const int lr = lane & 15, lk = lane >> 4;

  __shared__ __align__(16) char sm[133376];

  for (int t = 0; t < 64; ++t) {
    const int rI = t & 1;
    const u16* hcat_r = rI ? a.hcat1 : a.hcat0;
    u16* hcat_w = rI ? a.hcat0 : a.hcat1;
    const float* hf_r = rI ? a.hf1 : a.hf0;
    float* hf_w = rI ? a.hf0 : a.hf1;

    // ================= phase 1: GRU (all 128 blocks) =================
    {
      const int logical = (bid & 7) * 16 + (bid >> 3);
      const int mg = logical & 3;
      const int nt = logical >> 2;
      const int m0 = mg * 64;
      const int mh = w & 1, cq = w >> 1;

      const int arow = w * 8 + (lane >> 3);
      const int acol8 = ((lane & 7) ^ (arow & 7)) * 8;
      const u16* aZ = a.za + (size_t)(m0 + arow) * 1024 + acol8;
      const u16* aH = hcat_r + (size_t)(m0 + arow) * 2048 + acol8;
      const u16* wtNt = a.wt + (size_t)nt * 48 * 12288;

      f4v accr0 = (f4v)(0.f), accr1 = (f4v)(0.f);
      f4v accu0 = (f4v)(0.f), accu1 = (f4v)(0.f);
      f4v acci0 = (f4v)(0.f), acci1 = (f4v)(0.f);
      f4v acch0 = (f4v)(0.f), acch1 = (f4v)(0.f);

#define G_STAGE(S) { \
    char* base = sm + ((S) % 3) * 32768; \
    const u16* ap = ((S) < 16) ? (aZ + (S) * 64) : (aH + ((S) - 16) * 64); \
    glds16(ap, base + w * 1024); \
    const u16* bsrc = wtNt + (size_t)(S) * 12288; \
    _Pragma("unroll") for (int jj = 0; jj < 3; ++jj) { \
      int c = w + jj * 8; \
      glds16(bsrc + c * 512 + lane * 8, base + 8192 + c * 1024); \
    } }

#define G_COMP(S, X0, X1) { \
    char* base = sm + ((S) % 3) * 32768; \
    _Pragma("unroll") for (int kk = 0; kk < 2; ++kk) { \
      int ch = kk * 4 + lk; \
      int r0 = mh * 32 + lr, r1 = mh * 32 + 16 + lr; \
      s8v a0 = *(const s8v*)(base + r0 * 128 + ((ch ^ (r0 & 7)) << 4)); \
      s8v a1 = *(const s8v*)(base + r1 * 128 + ((ch ^ (r1 & 7)) << 4)); \
      int boff = 8192 + ch * 1024 + ((cq * 16 + lr) << 4); \
      s8v br = *(const s8v*)(base + boff); \
      s8v bu = *(const s8v*)(base + boff + 8192); \
      s8v bx = *(const s8v*)(base + boff + 16384); \
      accr0 = MFMA16(a0, br, accr0, 0, 0, 0); \
      accr1 = MFMA16(a1, br, accr1, 0, 0, 0); \
      accu0 = MFMA16(a0, bu, accu0, 0, 0, 0); \
      accu1 = MFMA16(a1, bu, accu1, 0, 0, 0); \
      X0 = MFMA16(a0, bx, X0, 0, 0, 0); \
      X1 = MFMA16(a1, bx, X1, 0, 0, 0); \
    } }

      G_STAGE(0)
      G_STAGE(1)
      for (int s = 0; s < 48; ++s) {
        if (s + 2 < 48) { G_STAGE(s + 2) }
        if (s < 46) asm volatile("s_waitcnt vmcnt(8)" ::: "memory");
        else if (s == 46) asm volatile("s_waitcnt vmcnt(4)" ::: "memory");
        else asm volatile("s_waitcnt vmcnt(0)" ::: "memory");
        RAW_BAR();
        if (s < 16) { G_COMP(s, acci0, acci1) }
        else { G_COMP(s, acch0, acch1) }
        RAW_BAR();
      }
#undef G_STAGE
#undef G_COMP

      const int col = nt * 64 + cq * 16 + lr;
      const float b_r = a.bih[col] + a.bhh[col];
      const float b_u = a.bih[2048 + col] + a.bhh[2048 + col];
      const float b_ci = a.bih[4096 + col];
      const float b_ch = a.bhh[4096 + col];
#define G_EPI(AR, AU, AI, AH, MO) \
  _Pragma("unroll") for (int r = 0; r < 4; ++r) { \
    int grow = m0 + mh * 32 + (MO) + lk * 4 + r; \
    float vr = AR[r] + b_r; \
    float vu = AU[r] + b_u; \
    float ic = AI[r] + b_ci; \
    float hc = AH[r] + b_ch; \
    float rg = 1.f / (1.f + expf(-vr)); \
    float ug = 1.f / (1.f + expf(-vu)); \
    float c = tanhf(ic + rg * hc); \
    float hold = hf_r[(size_t)grow * 2048 + col]; \
    float h1 = (1.f - ug) * c + ug * hold; \
    hf_w[(size_t)grow * 2048 + col] = h1; \
    hcat_w[(size_t)grow * 2048 + col] = f2bf(h1); \
    a.out_feat[(size_t)(t * 256 + grow) * 2112 + col] = h1; \
  }
      G_EPI(accr0, accu0, acci0, acch0, 0)
      G_EPI(accr1, accu1, acci1, acch1, 16)
#undef G_EPI
    }
    grid.sync();

    // ================= phase 2: post GEMM (all 128 blocks) =================
    {
      const int logical = (bid & 7) * 16 + (bid >> 3);
      const int mg = logical & 7, nt = logical >> 3;
      const int m0 = mg * 32;
      const int mh = w & 1, cq = w >> 1;

      const int arow = 8 * w + (lane >> 3);  // valid for w<4
      const int acol8 = ((lane & 7) ^ (arow & 7)) * 8;
      const u16* aSrc = hcat_w + (size_t)(m0 + arow) * 2048 + acol8;
      const u16* wpNt = a.posthP + (size_t)nt * 32 * 4096;
      const u16* epart_t = a.e_part + (size_t)t * 262144;

      f4v acc = (f4v)(0.f);

#define P_STAGE(BB, S) { \
    char* base = sm + (BB) * 12288; \
    if (w < 4) glds16(aSrc + (S) * 64, base + w * 1024); \
    glds16(wpNt + (size_t)(S) * 4096 + (w * 64 + lane) * 8, base + 4096 + w * 1024); }

#define P_COMP(BB) { \
    char* base = sm + (BB) * 12288; \
    _Pragma("unroll") for (int kk = 0; kk < 2; ++kk) { \
      int ch = kk * 4 + lk; \
      int r = mh * 16 + lr; \
      s8v av = *(const s8v*)(base + r * 128 + ((ch ^ (r & 7)) << 4)); \
      s8v bv = *(const s8v*)(base + 4096 + ch * 1024 + ((cq * 16 + lr) << 4)); \
      acc = MFMA16(av, bv, acc, 0, 0, 0); \
    } }

      P_STAGE(0, 0)
      for (int s = 0; s < 31; ++s) {
        P_STAGE((s + 1) & 1, s + 1)
        if (w < 4) { asm volatile("s_waitcnt vmcnt(2)" ::: "memory"); }
        else { asm volatile("s_waitcnt vmcnt(1)" ::: "memory"); }
        RAW_BAR();
        P_COMP(s & 1)
        RAW_BAR();
      }
      {
        asm volatile("s_waitcnt vmcnt(0)" ::: "memory");
        RAW_BAR();
        P_COMP(1)
      }
#undef P_STAGE
#undef P_COMP
      const int col = nt * 64 + cq * 16 + lr;
#pragma unroll
      for (int r = 0; r < 4; ++r) {
        int grow = m0 + mh * 16 + lk * 4 + r;
        float v = acc[r] + a.post_h_b[col] + bf2f(epart_t[(size_t)grow * 1024 + col]);
        a.xbuf[(size_t)grow * 1024 + col] = v;
      }
    }
    grid.sync();

    // ================= phase 3: postz (blocks 0..7) =================
    if (bid < 8) {
      const int m0 = bid * 32;
      float* posts_t = a.out_posts + (size_t)t * 32768;
      const float* noise_t = a.noise + (size_t)t * 16384;
      float* zout = a.out_z + (size_t)t * 16384;
      const float* act_t = a.actions + (size_t)(t + 1 < 64 ? t + 1 : t) * 2560;
      const float* xb = a.xbuf;

      // LDS overlay
      char* AsB = sm;                      // [2][2048] u16
      char* BsB = sm + 8192;               // [2][8192] u16
      float* ps = (float*)(sm + 40960);    // [32][132]
      float* lmu = (float*)(sm + 57856);
      float* lrsd = (float*)(sm + 57984);
      char* zblB = sm + 58112;             // [2048] u16
      float* ash = (float*)(sm + 62208);   // [320]
      char* zal = sm + 63488;              // [65536]
      float* zmu = (float*)(sm + 129024);
      float* zrsd = (float*)(sm + 129152);
      float* psum = (float*)(sm + 129280); // [16][32]
      float* qsum = (float*)(sm + 131328); // [16][32]

      if (tid < 320) ash[tid] = act_t[m0 * 10 + tid];
      {
        int row = tid >> 4, sg = tid & 15;
        const float4* xp = (const float4*)(xb + (size_t)(m0 + row) * 1024 + sg * 64);
        float s = 0.f, q = 0.f;
#pragma unroll
        for (int i = 0; i < 16; ++i) {
          float4 v = xp[i];
          s += v.x + v.y + v.z + v.w;
          q += v.x * v.x + v.y * v.y + v.z * v.z + v.w * v.w;
        }
#pragma unroll
        for (int o = 1; o < 16; o <<= 1) {
          s += __shfl_xor(s, o);
          q += __shfl_xor(q, o);
        }
        if (sg == 0) {
          float mu = s * (1.f / 1024.f);
          lmu[row] = mu;
          lrsd[row] = rsqrtf(q * (1.f / 1024.f) - mu * mu + LN_EPS);
        }
      }
      __syncthreads();

#define Z_STAGEA(BB, S) if (tid < 256) { \
    int row = tid >> 3, k8 = tid & 7; \
    const float* xp = xb + (size_t)(m0 + row) * 1024 + (S) * 64 + k8 * 8; \
    float mu = lmu[row], rs = lrsd[row]; \
    s8v v; \
    _Pragma("unroll") for (int e = 0; e < 8; ++e) { \
      int c = (S) * 64 + k8 * 8 + e; \
      float y = (xp[e] - mu) * rs * a.ln_post_s[c] + a.ln_post_b[c]; \
      y = y > 0.f ? y : expm1f(y); \
      v[e] = (short)f2bf(y); \
    } \
    *(s8v*)(AsB + (BB) * 4096 + row * 128 + ((k8 ^ (row & 7)) * 16)) = v; }

#define Z_STAGEB(BB, S) { \
    const u16* bsrc = a.postwP + (size_t)(S) * 8192; \
    glds16(bsrc + (w * 2) * 512 + lane * 8, BsB + (BB) * 16384 + w * 2048); \
    glds16(bsrc + (w * 2 + 1) * 512 + lane * 8, BsB + (BB) * 16384 + w * 2048 + 1024); }

      f4v acc0 = (f4v)(0.f), acc1 = (f4v)(0.f);
      Z_STAGEA(0, 0)
      Z_STAGEB(0, 0)
      int buf = 0;
      for (int s = 0; s < 16; ++s) {
        if (s + 1 < 16) {
          Z_STAGEA(buf ^ 1, s + 1)
          Z_STAGEB(buf ^ 1, s + 1)
          asm volatile("s_waitcnt vmcnt(2) lgkmcnt(0)" ::: "memory");
        } else {
          asm volatile("s_waitcnt vmcnt(0) lgkmcnt(0)" ::: "memory");
        }
        RAW_BAR();
#pragma unroll
        for (int kk = 0; kk < 2; ++kk) {
          int ch = kk * 4 + lk;
          int r0 = lr, r1 = 16 + lr;
          s8v a0 = *(const s8v*)(AsB + buf * 4096 + r0 * 128 + ((ch ^ (r0 & 7)) * 16));
          s8v a1 = *(const s8v*)(AsB + buf * 4096 + r1 * 128 + ((ch ^ (r1 & 7)) * 16));
          s8v b = *(const s8v*)(BsB + buf * 16384 + ch * 2048 + (w * 16 + lr) * 16);
          acc0 = MFMA16(a0, b, acc0, 0, 0, 0);
          acc1 = MFMA16(a1, b, acc1, 0, 0, 0);
        }
        __builtin_amdgcn_s_barrier();
        buf ^= 1;
      }
#undef Z_STAGEA
#undef Z_STAGEB

      {
        int colp = w * 16 + lr;
#pragma unroll
        for (int r = 0; r < 4; ++r) {
          int row0 = lk * 4 + r;
          float v0 = acc0[r] + a.post_b[colp];
          posts_t[(size_t)(m0 + row0) * 128 + colp] = v0;
          ps[row0 * 132 + colp] = v0;
          float v1 = acc1[r] + a.post_b[colp];
          posts_t[(size_t)(m0 + 16 + row0) * 128 + colp] = v1;
          ps[(16 + row0) * 132 + colp] = v1;
        }
      }
      __syncthreads();
#pragma unroll
      for (int q = 0; q < 4; ++q) {
        int e = q * 512 + tid;
        int row = e >> 6, j = e & 63;
        float mean = ps[row * 132 + j], sraw = ps[row * 132 + 64 + j];
        float sd = 2.f / (1.f + expf(-sraw)) + 0.1f;
        float z = mean + sd * noise_t[(m0 + row) * 64 + j];
        zout[(m0 + row) * 64 + j] = z;
        a.out_feat[(size_t)(t * 256 + m0 + row) * 2112 + 2048 + j] = z;
        *(u16*)(zblB + row * 128 + (((j >> 3) ^ (row & 7)) << 4) + (j & 7) * 2) =
            f2bf(z);
      }
      __syncthreads();

      // za a-part (cols 512..1023)
      {
        float accv[32];
#pragma unroll
        for (int r = 0; r < 32; ++r) accv[r] = 0.f;
#pragma unroll
        for (int k = 0; k < 10; ++k) {
          float wv = a.awT[k * 512 + tid];
#pragma unroll
          for (int r = 0; r < 32; ++r) accv[r] += ash[r * 10 + k] * wv;
        }
        int c = 512 + tid;
        int chs = c >> 3, cb = (c & 7) * 2;
#pragma unroll
        for (int r = 0; r < 32; ++r)
          *(u16*)(zal + r * 2048 + ((chs ^ (r & 7)) << 4) + cb) = f2bf(accv[r]);
      }
      // za z-part (cols 0..511): MFMA over 4 col-chunks of 128
      for (int c4 = 0; c4 < 4; ++c4) {
        glds16(a.zwP + c4 * 8192 + (w * 2) * 512 + lane * 8, BsB + w * 2048);
        glds16(a.zwP + c4 * 8192 + (w * 2 + 1) * 512 + lane * 8,
               BsB + w * 2048 + 1024);
        asm volatile("s_waitcnt vmcnt(0)" ::: "memory");
        RAW_BAR();
        f4v z0 = (f4v)(0.f), z1 = (f4v)(0.f);
#pragma unroll
        for (int kk = 0; kk < 2; ++kk) {
          int ch = kk * 4 + lk;
          int r0 = lr, r1 = 16 + lr;
          s8v a0 = *(const s8v*)(zblB + r0 * 128 + ((ch ^ (r0 & 7)) << 4));
          s8v a1 = *(const s8v*)(zblB + r1 * 128 + ((ch ^ (r1 & 7)) << 4));
          s8v b = *(const s8v*)(BsB + ch * 2048 + (w * 16 + lr) * 16);
          z0 = MFMA16(a0, b, z0, 0, 0, 0);
          z1 = MFMA16(a1, b, z1, 0, 0, 0);
        }
        int zcol = c4 * 128 + w * 16 + lr;
        int chz = zcol >> 3, cbz = (zcol & 7) * 2;
        float zbias = a.z_mlp_b[zcol];
#pragma unroll
        for (int r = 0; r < 4; ++r) {
          int ra = lk * 4 + r, rb = 16 + lk * 4 + r;
          *(u16*)(zal + ra * 2048 + ((chz ^ (ra & 7)) << 4) + cbz) =
              f2bf(z0[r] + zbias);
          *(u16*)(zal + rb * 2048 + ((chz ^ (rb & 7)) << 4) + cbz) =
              f2bf(z1[r] + zbias);
        }
        RAW_BAR();
      }
      __syncthreads();
      // za LN stats
      {
        int row = tid & 31, g = tid >> 5;
        float s = 0.f, q = 0.f;
#pragma unroll
        for (int jj = 0; jj < 8; ++jj) {
          int chunk = g * 8 + jj;
          s8v v = *(const s8v*)(zal + row * 2048 + ((chunk ^ (row & 7)) << 4));
#pragma unroll
          for (int e = 0; e < 8; ++e) {
            float x = bf2f((u16)v[e]);
            s += x;
            q += x * x;
          }
        }
        psum[g * 32 + row] = s;
        qsum[g * 32 + row] = q;
        __syncthreads();
        if (tid < 32) {
          float ss = 0.f, qq = 0.f;
#pragma unroll
          for (int gg = 0; gg < 16; ++gg) {
            ss += psum[gg * 32 + tid];
            qq += qsum[gg * 32 + tid];
          }
          float mu = ss * (1.f / 1024.f);
          zmu[tid] = mu;
          zrsd[tid] = rsqrtf(qq * (1.f / 1024.f) - mu * mu + LN_EPS);
        }
      }
      __syncthreads();
      // apply LN+ELU, write za
      {
        int row = tid >> 4, g = tid & 15;
        float mu = zmu[row], rs = zrsd[row];
        u16* dst = a.za + (size_t)(m0 + row) * 1024 + g * 64;
#pragma unroll
        for (int jj = 0; jj < 8; ++jj) {
          int chunk = g * 8 + jj;
          s8v v = *(const s8v*)(zal + row * 2048 + ((chunk ^ (row & 7)) << 4));
          s8v o;
#pragma unroll
          for (int e = 0; e < 8; ++e) {
            int c = chunk * 8 + e;
            float y = (bf2f((u16)v[e]) - mu) * rs * a.ln_za_s[c] + a.ln_za_b[c];
            y = y > 0.f ? y : expm1f(y);
            o[e] = (short)f2bf(y);
          }
          *(s8v*)(dst + jj * 8) = o;
        }
      }
    }
    grid.sync();
  }
}

// ---------------- batched 8-wave GEMM (embed / prior phases) ----------------
template <bool AF32, bool OUTBF16>
__global__ __launch_bounds__(512) void k_gemm8(
    const void* __restrict__ Av, int lda, const u16* __restrict__ Bw, int ldb,
    int nstage, float* __restrict__ Cf, u16* __restrict__ Cb, int ldc,
    const float* __restrict__ bias) {
  const int bx = blockIdx.x, by = blockIdx.y;
  const int tid = threadIdx.x;
  const int m0 = bx * 64;
  const int n0 = by * 128;
  __shared__ __align__(16) u16 As[64][72];
  __shared__ __align__(16) u16 Bs[128][72];
  const int lane = tid & 63;
  const int w = tid >> 6;
  const int wr = w >> 2;
  const int wc = w & 3;
  const int lr = lane & 15;
  const int lk = lane >> 4;

  f4v acc[2][2];
#pragma unroll
  for (int m = 0; m < 2; ++m)
#pragma unroll
    for (int n = 0; n < 2; ++n) acc[m][n] = (f4v)(0.0f);

  for (int s = 0; s < nstage; ++s) {
    const int k0 = s << 6;
    {
      int row = tid >> 3, k8 = (tid & 7) << 3;
      if (AF32) {
        const float* ap = (const float*)Av + (size_t)(m0 + row) * lda + k0 + k8;
        float4 f0 = *(const float4*)ap;
        float4 f1 = *(const float4*)(ap + 4);
        s8v v;
        v[0] = (short)f2bf(f0.x); v[1] = (short)f2bf(f0.y);
        v[2] = (short)f2bf(f0.z); v[3] = (short)f2bf(f0.w);
        v[4] = (short)f2bf(f1.x); v[5] = (short)f2bf(f1.y);
        v[6] = (short)f2bf(f1.z); v[7] = (short)f2bf(f1.w);
        *(s8v*)&As[row][k8] = v;
      } else {
        *(s8v*)&As[row][k8] =
            *(const s8v*)((const u16*)Av + (size_t)(m0 + row) * lda + k0 + k8);
      }
    }
#pragma unroll
    for (int it = 0; it < 2; ++it) {
      int c = tid + it * 512;
      int row = c >> 3, k8 = (c & 7) << 3;
      *(s8v*)&Bs[row][k8] = *(const s8v*)(Bw + (size_t)(n0 + row) * ldb + k0 + k8);
    }
    __syncthreads();
#pragma unroll
    for (int kk = 0; kk < 2; ++kk) {
      const int koff = kk * 32 + lk * 8;
      s8v a[2], b[2];
      a[0] = *(const s8v*)&As[wr * 32 + lr][koff];
      a[1] = *(const s8v*)&As[wr * 32 + 16 + lr][koff];
      b[0] = *(const s8v*)&Bs[wc * 32 + lr][koff];
      b[1] = *(const s8v*)&Bs[wc * 32 + 16 + lr][koff];
#pragma unroll
      for (int m = 0; m < 2; ++m)
#pragma unroll
        for (int n = 0; n < 2; ++n)
          acc[m][n] = MFMA16(a[m], b[n], acc[m][n], 0, 0, 0);
    }
    __syncthreads();
  }
#pragma unroll
  for (int m = 0; m < 2; ++m) {
#pragma unroll
    for (int n = 0; n < 2; ++n) {
#pragma unroll
      for (int r = 0; r < 4; ++r) {
        int row = m0 + wr * 32 + m * 16 + lk * 4 + r;
        int col = n0 + wc * 32 + n * 16 + lr;
        float v = acc[m][n][r];
        if (bias) v += bias[col];
        if (OUTBF16)
          Cb[(size_t)row * ldc + col] = f2bf(v);
        else
          Cf[(size_t)row * ldc + col] = v;
      }
    }
  }
}

// ---------------- LN + ELU (rows of 1024), bf16 in/out ----------------
__global__ __launch_bounds__(256) void k_lnelu(const u16* __restrict__ xsrc,
                                               const float* __restrict__ s,
                                               const float* __restrict__ bb,
                                               u16* __restrict__ out) {
  int row = blockIdx.x, tid = threadIdx.x;
  __shared__ float red[256];
  float v[4];
#pragma unroll
  for (int i = 0; i < 4; ++i) {
    size_t idx = (size_t)row * 1024 + tid + i * 256;
    v[i] = bf2f(xsrc[idx]);
  }
  float sm = v[0] + v[1] + v[2] + v[3];
  red[tid] = sm;
  __syncthreads();
  for (int o = 128; o > 0; o >>= 1) {
    if (tid < o) red[tid] += red[tid + o];
    __syncthreads();
  }
  float mu = red[0] * (1.0f / 1024.0f);
  __syncthreads();
  float q = 0.f;
#pragma unroll
  for (int i = 0; i < 4; ++i) {
    float d = v[i] - mu;
    q += d * d;
  }
  red[tid] = q;
  __syncthreads();
  for (int o = 128; o > 0; o >>= 1) {
    if (tid < o) red[tid] += red[tid + o];
    __syncthreads();
  }
  float rs = rsqrtf(red[0] * (1.0f / 1024.0f) + LN_EPS);
#pragma unroll
  for (int i = 0; i < 4; ++i) {
    int c = tid + i * 256;
    float y = (v[i] - mu) * rs * s[c] + bb[c];
    y = y > 0.f ? y : expm1f(y);
    out[(size_t)row * 1024 + c] = f2bf(y);
  }
}

extern "C" void kernel_launch(void* const* d_in, const int* in_sizes, int n_in,
                              void* d_out, int out_size, void* d_ws,
                              size_t ws_size, hipStream_t stream) {
  const float* embeds = (const float*)d_in[0];
  const float* actions = (const float*)d_in[1];
  const float* h_t = (const float*)d_in[2];
  const float* z_t = (const float*)d_in[3];
  const float* noise = (const float*)d_in[4];
  const float* z_mlp_w = (const float*)d_in[5];
  const float* z_mlp_b = (const float*)d_in[6];
  const float* a_mlp_w = (const float*)d_in[7];
  const float* ln_za_s = (const float*)d_in[8];
  const float* ln_za_b = (const float*)d_in[9];
  const float* gru_wih = (const float*)d_in[10];
  const float* gru_whh = (const float*)d_in[11];
  const float* gru_bih = (const float*)d_in[12];
  const float* gru_bhh = (const float*)d_in[13];
  const float* post_h_w = (const float*)d_in[14];
  const float* post_h_b = (const float*)d_in[15];
  const float* post_e_w = (const float*)d_in[16];
  const float* post_e_b = (const float*)d_in[17];
  const float* ln_post_s = (const float*)d_in[18];
  const float* ln_post_b = (const float*)d_in[19];
  const float* post_w = (const float*)d_in[20];
  const float* post_b = (const float*)d_in[21];
  const float* prior_h_w = (const float*)d_in[22];
  const float* prior_h_b = (const float*)d_in[23];
  const float* ln_prior_s = (const float*)d_in[24];
  const float* ln_prior_b = (const float*)d_in[25];
  const float* prior_w = (const float*)d_in[26];
  const float* prior_b = (const float*)d_in[27];

  float* out = (float*)d_out;
  float* out_priors = out;           // [64,256,128]
  float* out_posts = out + 2097152;  // [64,256,128]
  float* out_z = out + 4194304;      // [64,256,64]
  float* out_feat = out + 5242880;   // [64,256,2112]

  char* ws = (char*)d_ws;
  size_t off = 0;
  auto alloc = [&](size_t bytes) {
    char* p = ws + off;
    off += (bytes + 255) & ~(size_t)255;
    return p;
  };
  char* regW = alloc((size_t)32 * 48 * 12288 * 2);  // 37.75 MB
  u16* wt = (u16*)regW;
  u16* prx_b = (u16*)regW;
  u16* posthP = (u16*)alloc((size_t)1024 * 2048 * 2);
  u16* postwP = (u16*)alloc((size_t)128 * 1024 * 2);
  u16* poste_b = (u16*)alloc((size_t)1024 * 1536 * 2);
  u16* priorh_b = (u16*)alloc((size_t)1024 * 2048 * 2);
  u16* priorw_b = (u16*)alloc((size_t)128 * 1024 * 2);
  u16* zwP = (u16*)alloc((size_t)512 * 64 * 2);
  float* awT = (float*)alloc((size_t)10 * 512 * 4);
  u16* hcat0 = (u16*)alloc((size_t)256 * 2048 * 2);
  u16* hcat1 = (u16*)alloc((size_t)256 * 2048 * 2);
  float* hf0 = (float*)alloc((size_t)256 * 2048 * 4);
  float* hf1 = (float*)alloc((size_t)256 * 2048 * 4);
  float* xbuf = (float*)alloc((size_t)256 * 1024 * 4);
  u16* za = (u16*)alloc((size_t)256 * 1024 * 2);
  char* regU = alloc((size_t)16384 * 1024 * 2);  // 33.55 MB
  u16* e_part = (u16*)regU;
  u16* p_pr = (u16*)regU;

  // ---- packing + conversions + h init + za(t=0) ----
  k_packgru<<<9216, 256, 0, stream>>>(gru_wih, gru_whh, wt);
  k_packB<<<1024, 256, 0, stream>>>(post_h_w, posthP, 2048, 64, 262144);
  k_packB<<<64, 256, 0, stream>>>(post_w, postwP, 1024, 128, 16384);
  k_packB<<<16, 256, 0, stream>>>(z_mlp_w, zwP, 64, 128, 4096);
  k_trA<<<20, 256, 0, stream>>>(a_mlp_w, awT);
  k_cvt<<<512, 256, 0, stream>>>(post_e_w, poste_b, 1024 * 1536);
  k_cvt<<<512, 256, 0, stream>>>(prior_h_w, priorh_b, 1024 * 2048);
  k_cvt<<<64, 256, 0, stream>>>(prior_w, priorw_b, 128 * 1024);
  k_hinit<<<2048, 256, 0, stream>>>(h_t, hf0, hcat0);
  k_za0<<<256, 256, 0, stream>>>(z_t, actions, z_mlp_w, z_mlp_b, a_mlp_w,
                                 ln_za_s, ln_za_b, za);

  // ---- batched embed projection: e_part = embeds@post_e_w^T + post_e_b ----
  k_gemm8<true, true><<<dim3(256, 8), 512, 0, stream>>>(
      embeds, 1536, poste_b, 1536, 24, nullptr, e_part, 1024, post_e_b);

  // ---- persistent cooperative scan (one launch for all 64 steps) ----
  ScanArgs sa;
  sa.wt = wt;
  sa.bih = gru_bih;
  sa.bhh = gru_bhh;
  sa.hcat0 = hcat0;
  sa.hcat1 = hcat1;
  sa.hf0 = hf0;
  sa.hf1 = hf1;
  sa.za = za;
  sa.posthP = posthP;
  sa.post_h_b = post_h_b;
  sa.e_part = e_part;
  sa.xbuf = xbuf;
  sa.postwP = postwP;
  sa.ln_post_s = ln_post_s;
  sa.ln_post_b = ln_post_b;
  sa.post_b = post_b;
  sa.out_posts = out_posts;
  sa.noise = noise;
  sa.out_z = out_z;
  sa.out_feat = out_feat;
  sa.zwP = zwP;
  sa.z_mlp_b = z_mlp_b;
  sa.awT = awT;
  sa.actions = actions;
  sa.ln_za_s = ln_za_s;
  sa.ln_za_b = ln_za_b;
  void* kargs[] = {(void*)&sa};
  hipLaunchCooperativeKernel((const void*)k_scan, dim3(128), dim3(512), kargs,
                             0, stream);

  // ---- batched prior head (wt/e_part dead; reuse regions) ----
  k_gemm8<true, true><<<dim3(256, 8), 512, 0, stream>>>(
      out_feat, 2112, priorh_b, 2048, 32, nullptr, prx_b, 1024, prior_h_b);
  k_lnelu<<<16384, 256, 0, stream>>>(prx_b, ln_prior_s, ln_prior_b, p_pr);
  k_gemm8<false, false><<<dim3(256, 1), 512, 0, stream>>>(
      p_pr, 1024, priorw_b, 1024, 16, out_priors, nullptr, 128, prior_b);
}

// Round 8
// 13016.267 us; speedup vs baseline: 1.0772x; 1.0772x over previous
//
#include <hip/hip_runtime.h>
#include <hip/hip_cooperative_groups.h>

#define LN_EPS 1e-3f

typedef short s8v __attribute__((ext_vector_type(8)));
typedef float f4v __attribute__((ext_vector_type(4)));
typedef unsigned short u16;

#define MFMA16 __builtin_amdgcn_mfma_f32_16x16x32_bf16

__device__ __forceinline__ u16 f2bf(float f) {
  unsigned int x = __float_as_uint(f);
  x += 0x7fffu + ((x >> 16) & 1u);
  return (u16)(x >> 16);
}
__device__ __forceinline__ float bf2f(u16 u) {
  return __uint_as_float(((unsigned int)u) << 16);
}

__device__ __forceinline__ void glds16(const u16* g, void* l) {
  __builtin_amdgcn_global_load_lds(
      (const __attribute__((address_space(1))) void*)g,
      (__attribute__((address_space(3))) void*)l, 16, 0, 0);
}

#define RAW_BAR() do { __builtin_amdgcn_s_barrier(); __builtin_amdgcn_sched_barrier(0); } while (0)

// ---- lightweight device-scope slot barrier (slots pre-zeroed each call) ----
__device__ __forceinline__ void gbar(unsigned* slots, int id, unsigned nb) {
  __syncthreads();
  if (threadIdx.x == 0) {
    unsigned* p = slots + id * 32;  // 128B stride, avoid false sharing
    __threadfence();  // release: drain + make prior writes device-visible
    __hip_atomic_fetch_add(p, 1u, __ATOMIC_RELEASE, __HIP_MEMORY_SCOPE_AGENT);
    while (__hip_atomic_load(p, __ATOMIC_RELAXED, __HIP_MEMORY_SCOPE_AGENT) < nb)
      __builtin_amdgcn_s_sleep(1);
    __threadfence();  // acquire: invalidate stale cache lines
  }
  __syncthreads();
}

__global__ void k_zero(unsigned* p, int n) {
  int i = blockIdx.x * 256 + threadIdx.x;
  if (i < n) p[i] = 0;
}

// ---------------- fp32 -> bf16 conversion ----------------
__global__ void k_cvt(const float* __restrict__ src, u16* __restrict__ dst, int n) {
  int i = blockIdx.x * blockDim.x + threadIdx.x;
  int stride = gridDim.x * blockDim.x;
  for (; i < n; i += stride) dst[i] = f2bf(src[i]);
}

// pack GRU weights: wt[nt(32)][s(48)][sub(3)][ch(8)][row(64)][8]
__global__ void k_packgru(const float* __restrict__ wih,
                          const float* __restrict__ whh, u16* __restrict__ wt) {
  int u = blockIdx.x * 256 + threadIdx.x;  // 16B units, total 2359296
  int nt = u / 73728;
  int r1 = u % 73728;
  int s = r1 / 1536;
  int r2 = r1 % 1536;
  int sub = r2 / 512;
  int r3 = r2 % 512;
  int ch = r3 / 64;
  int row = r3 % 64;
  int j = nt * 64 + row;
  int kbase = s * 64 + ch * 8;
  s8v v;
#pragma unroll
  for (int e = 0; e < 8; ++e) {
    int kk = kbase + e;
    float x;
    if (sub == 0) {
      x = kk < 1024 ? wih[(size_t)j * 1024 + kk] : whh[(size_t)j * 2048 + kk - 1024];
    } else if (sub == 1) {
      int jj = 2048 + j;
      x = kk < 1024 ? wih[(size_t)jj * 1024 + kk] : whh[(size_t)jj * 2048 + kk - 1024];
    } else {
      int jj = 4096 + j;
      x = (s < 16) ? wih[(size_t)jj * 1024 + kk] : whh[(size_t)jj * 2048 + kk - 1024];
    }
    v[e] = (short)f2bf(x);
  }
  *(s8v*)(wt + (size_t)u * 8) = v;
}

// generic chunk-linear pack: dst[nt][s][ch(8)][row(BN)][8] from src[N][K] f32
__global__ void k_packB(const float* __restrict__ src, u16* __restrict__ dst,
                        int K, int BN, int total) {
  int u = blockIdx.x * 256 + threadIdx.x;
  if (u >= total) return;
  int ns = K >> 6;
  int perNt = ns * 8 * BN;
  int nt = u / perNt;
  int r1 = u % perNt;
  int s = r1 / (8 * BN);
  int r2 = r1 % (8 * BN);
  int ch = r2 / BN;
  int row = r2 % BN;
  int j = nt * BN + row;
  int k = s * 64 + ch * 8;
  const float* sp = src + (size_t)j * K + k;
  s8v v;
#pragma unroll
  for (int e = 0; e < 8; ++e) v[e] = (short)f2bf(sp[e]);
  *(s8v*)(dst + (size_t)u * 8) = v;
}

// awT[k*512+c] = aw[c*10+k]
__global__ void k_trA(const float* __restrict__ aw, float* __restrict__ awT) {
  int i = blockIdx.x * 256 + threadIdx.x;
  if (i >= 5120) return;
  int k = i >> 9, c = i & 511;
  awT[i] = aw[c * 10 + k];
}

// h0 -> hf (f32) and hcat (bf16)
__global__ void k_hinit(const float* __restrict__ h0, float* __restrict__ hf,
                        u16* __restrict__ hcat) {
  int i = blockIdx.x * 256 + threadIdx.x;  // 524288
  float v = h0[i];
  hf[i] = v;
  hcat[i] = f2bf(v);
}

// ---------------- t=0 za: elu(LN(concat(z@zw^T+zb, a@aw^T))) ----------------
__global__ __launch_bounds__(256) void k_za0(
    const float* __restrict__ zsrc, const float* __restrict__ act,
    const float* __restrict__ zw, const float* __restrict__ zb,
    const float* __restrict__ aw, const float* __restrict__ lns,
    const float* __restrict__ lnb, u16* __restrict__ za) {
  const int b = blockIdx.x, tid = threadIdx.x;
  __shared__ float zsh[64];
  __shared__ float ash[12];
  __shared__ float wred[8];
  if (tid < 64) zsh[tid] = zsrc[b * 64 + tid];
  if (tid < 10) ash[tid] = act[b * 10 + tid];
  __syncthreads();
  float x[4];
#pragma unroll
  for (int i = 0; i < 2; ++i) {
    int c = tid + i * 256;
    const float4* wp = (const float4*)(zw + c * 64);
    float a = zb[c];
#pragma unroll
    for (int k = 0; k < 16; ++k) {
      float4 v = wp[k];
      a += zsh[k * 4] * v.x + zsh[k * 4 + 1] * v.y + zsh[k * 4 + 2] * v.z +
           zsh[k * 4 + 3] * v.w;
    }
    x[i] = a;
  }
#pragma unroll
  for (int i = 2; i < 4; ++i) {
    int c2 = tid + (i - 2) * 256;
    const float* wp = aw + c2 * 10;
    float a = 0.f;
#pragma unroll
    for (int k = 0; k < 10; ++k) a += ash[k] * wp[k];
    x[i] = a;
  }
  float s = x[0] + x[1] + x[2] + x[3];
#pragma unroll
  for (int o = 1; o < 64; o <<= 1) s += __shfl_xor(s, o);
  if ((tid & 63) == 0) wred[tid >> 6] = s;
  __syncthreads();
  float mu = (wred[0] + wred[1] + wred[2] + wred[3]) * (1.f / 1024.f);
  float q = 0.f;
#pragma unroll
  for (int i = 0; i < 4; ++i) {
    float d = x[i] - mu;
    q += d * d;
  }
#pragma unroll
  for (int o = 1; o < 64; o <<= 1) q += __shfl_xor(q, o);
  if ((tid & 63) == 0) wred[4 + (tid >> 6)] = q;
  __syncthreads();
  float rs = rsqrtf((wred[4] + wred[5] + wred[6] + wred[7]) * (1.f / 1024.f) + LN_EPS);
  int cols[4] = {tid, tid + 256, 512 + tid, 768 + tid};
#pragma unroll
  for (int i = 0; i < 4; ++i) {
    int c = cols[i];
    float y = (x[i] - mu) * rs * lns[c] + lnb[c];
    y = y > 0.f ? y : expm1f(y);
    za[(size_t)b * 1024 + c] = f2bf(y);
  }
}

// ---------------- persistent cooperative scan kernel ----------------
struct ScanArgs {
  const u16* wt;
  const float* bih;
  const float* bhh;
  u16* hcat0;
  u16* hcat1;
  float* hf0;
  float* hf1;
  u16* za;
  const u16* posthP;
  const float* post_h_b;
  const u16* e_part;
  float* xbuf;
  const u16* postwP;
  const float* ln_post_s;
  const float* ln_post_b;
  const float* post_b;
  float* out_posts;
  const float* noise;
  float* out_z;
  float* out_feat;
  const u16* zwP;
  const float* z_mlp_b;
  const float* awT;
  const float* actions;
  const float* ln_za_s;
  const float* ln_za_b;
  unsigned* bars;
};

__global__ __launch_bounds__(512) void k_scan(ScanArgs a) {
  const int bid = blockIdx.x;
  const int tid = threadIdx.x;
  const int lane = tid & 63;
  const int w = tid >> 6;  // 0..7
  const int lr = lane & 15, lk = lane >> 4;

  __shared__ __align__(16) char sm[133376];

  for (int t = 0; t < 64; ++t) {
    const int rI = t & 1;
    const u16* hcat_r = rI ? a.hcat1 : a.hcat0;
    u16* hcat_w = rI ? a.hcat0 : a.hcat1;
    const float* hf_r = rI ? a.hf1 : a.hf0;
    float* hf_w = rI ? a.hf0 : a.hf1;

    // ================= phase 1: GRU (all 128 blocks) =================
    {
      const int logical = (bid & 7) * 16 + (bid >> 3);
      const int mg = logical & 3;
      const int nt = logical >> 2;
      const int m0 = mg * 64;
      const int mh = w & 1, cq = w >> 1;

      const int arow = w * 8 + (lane >> 3);
      const int acol8 = ((lane & 7) ^ (arow & 7)) * 8;
      const u16* aZ = a.za + (size_t)(m0 + arow) * 1024 + acol8;
      const u16* aH = hcat_r + (size_t)(m0 + arow) * 2048 + acol8;
      const u16* wtNt = a.wt + (size_t)nt * 48 * 12288;

      f4v accr0 = (f4v)(0.f), accr1 = (f4v)(0.f);
      f4v accu0 = (f4v)(0.f), accu1 = (f4v)(0.f);
      f4v acci0 = (f4v)(0.f), acci1 = (f4v)(0.f);
      f4v acch0 = (f4v)(0.f), acch1 = (f4v)(0.f);

#define G_STAGE(S) { \
    char* base = sm + ((S) % 3) * 32768; \
    const u16* ap = ((S) < 16) ? (aZ + (S) * 64) : (aH + ((S) - 16) * 64); \
    glds16(ap, base + w * 1024); \
    const u16* bsrc = wtNt + (size_t)(S) * 12288; \
    _Pragma("unroll") for (int jj = 0; jj < 3; ++jj) { \
      int c = w + jj * 8; \
      glds16(bsrc + c * 512 + lane * 8, base + 8192 + c * 1024); \
    } }

#define G_COMP(S, X0, X1) { \
    char* base = sm + ((S) % 3) * 32768; \
    _Pragma("unroll") for (int kk = 0; kk < 2; ++kk) { \
      int ch = kk * 4 + lk; \
      int r0 = mh * 32 + lr, r1 = mh * 32 + 16 + lr; \
      s8v a0 = *(const s8v*)(base + r0 * 128 + ((ch ^ (r0 & 7)) << 4)); \
      s8v a1 = *(const s8v*)(base + r1 * 128 + ((ch ^ (r1 & 7)) << 4)); \
      int boff = 8192 + ch * 1024 + ((cq * 16 + lr) << 4); \
      s8v br = *(const s8v*)(base + boff); \
      s8v bu = *(const s8v*)(base + boff + 8192); \
      s8v bx = *(const s8v*)(base + boff + 16384); \
      accr0 = MFMA16(a0, br, accr0, 0, 0, 0); \
      accr1 = MFMA16(a1, br, accr1, 0, 0, 0); \
      accu0 = MFMA16(a0, bu, accu0, 0, 0, 0); \
      accu1 = MFMA16(a1, bu, accu1, 0, 0, 0); \
      X0 = MFMA16(a0, bx, X0, 0, 0, 0); \
      X1 = MFMA16(a1, bx, X1, 0, 0, 0); \
    } }

      G_STAGE(0)
      G_STAGE(1)
      for (int s = 0; s < 48; ++s) {
        if (s + 2 < 48) { G_STAGE(s + 2) }
        if (s < 46) asm volatile("s_waitcnt vmcnt(8)" ::: "memory");
        else if (s == 46) asm volatile("s_waitcnt vmcnt(4)" ::: "memory");
        else asm volatile("s_waitcnt vmcnt(0)" ::: "memory");
        RAW_BAR();
        if (s < 16) { G_COMP(s, acci0, acci1) }
        else { G_COMP(s, acch0, acch1) }
        RAW_BAR();
      }
#undef G_STAGE
#undef G_COMP

      const int col = nt * 64 + cq * 16 + lr;
      const float b_r = a.bih[col] + a.bhh[col];
      const float b_u = a.bih[2048 + col] + a.bhh[2048 + col];
      const float b_ci = a.bih[4096 + col];
      const float b_ch = a.bhh[4096 + col];
#define G_EPI(AR, AU, AI, AH, MO) \
  _Pragma("unroll") for (int r = 0; r < 4; ++r) { \
    int grow = m0 + mh * 32 + (MO) + lk * 4 + r; \
    float vr = AR[r] + b_r; \
    float vu = AU[r] + b_u; \
    float ic = AI[r] + b_ci; \
    float hc = AH[r] + b_ch; \
    float rg = 1.f / (1.f + expf(-vr)); \
    float ug = 1.f / (1.f + expf(-vu)); \
    float c = tanhf(ic + rg * hc); \
    float hold = hf_r[(size_t)grow * 2048 + col]; \
    float h1 = (1.f - ug) * c + ug * hold; \
    hf_w[(size_t)grow * 2048 + col] = h1; \
    hcat_w[(size_t)grow * 2048 + col] = f2bf(h1); \
    a.out_feat[(size_t)(t * 256 + grow) * 2112 + col] = h1; \
  }
      G_EPI(accr0, accu0, acci0, acch0, 0)
      G_EPI(accr1, accu1, acci1, acch1, 16)
#undef G_EPI
    }
    gbar(a.bars, t * 3 + 0, 128);

    // ================= phase 2: post GEMM (all 128 blocks) =================
    {
      const int logical = (bid & 7) * 16 + (bid >> 3);
      const int mg = logical & 7, nt = logical >> 3;
      const int m0 = mg * 32;
      const int mh = w & 1, cq = w >> 1;

      const int arow = 8 * w + (lane >> 3);  // valid for w<4
      const int acol8 = ((lane & 7) ^ (arow & 7)) * 8;
      const u16* aSrc = hcat_w + (size_t)(m0 + arow) * 2048 + acol8;
      const u16* wpNt = a.posthP + (size_t)nt * 32 * 4096;
      const u16* epart_t = a.e_part + (size_t)t * 262144;

      f4v acc = (f4v)(0.f);

#define P_STAGE(BB, S) { \
    char* base = sm + (BB) * 12288; \
    if (w < 4) glds16(aSrc + (S) * 64, base + w * 1024); \
    glds16(wpNt + (size_t)(S) * 4096 + (w * 64 + lane) * 8, base + 4096 + w * 1024); }

#define P_COMP(BB) { \
    char* base = sm + (BB) * 12288; \
    _Pragma("unroll") for (int kk = 0; kk < 2; ++kk) { \
      int ch = kk * 4 + lk; \
      int r = mh * 16 + lr; \
      s8v av = *(const s8v*)(base + r * 128 + ((ch ^ (r & 7)) << 4)); \
      s8v bv = *(const s8v*)(base + 4096 + ch * 1024 + ((cq * 16 + lr) << 4)); \
      acc = MFMA16(av, bv, acc, 0, 0, 0); \
    } }

      P_STAGE(0, 0)
      for (int s = 0; s < 31; ++s) {
        P_STAGE((s + 1) & 1, s + 1)
        if (w < 4) { asm volatile("s_waitcnt vmcnt(2)" ::: "memory"); }
        else { asm volatile("s_waitcnt vmcnt(1)" ::: "memory"); }
        RAW_BAR();
        P_COMP(s & 1)
        RAW_BAR();
      }
      {
        asm volatile("s_waitcnt vmcnt(0)" ::: "memory");
        RAW_BAR();
        P_COMP(1)
      }
#undef P_STAGE
#undef P_COMP
      const int col = nt * 64 + cq * 16 + lr;
#pragma unroll
      for (int r = 0; r < 4; ++r) {
        int grow = m0 + mh * 16 + lk * 4 + r;
        float v = acc[r] + a.post_h_b[col] + bf2f(epart_t[(size_t)grow * 1024 + col]);
        a.xbuf[(size_t)grow * 1024 + col] = v;
      }
    }
    gbar(a.bars, t * 3 + 1, 128);

    // ================= phase 3: postz (blocks 0..7) =================
    if (bid < 8) {
      const int m0 = bid * 32;
      float* posts_t = a.out_posts + (size_t)t * 32768;
      const float* noise_t = a.noise + (size_t)t * 16384;
      float* zout = a.out_z + (size_t)t * 16384;
      const float* act_t = a.actions + (size_t)(t + 1 < 64 ? t + 1 : t) * 2560;
      const float* xb = a.xbuf;

      // LDS overlay
      char* AsB = sm;                      // [2][2048] u16
      char* BsB = sm + 8192;               // [2][8192] u16
      float* ps = (float*)(sm + 40960);    // [32][132]
      float* lmu = (float*)(sm + 57856);
      float* lrsd = (float*)(sm + 57984);
      char* zblB = sm + 58112;             // [2048] u16
      float* ash = (float*)(sm + 62208);   // [320]
      char* zal = sm + 63488;              // [65536]
      float* zmu = (float*)(sm + 129024);
      float* zrsd = (float*)(sm + 129152);
      float* psum = (float*)(sm + 129280); // [16][32]
      float* qsum = (float*)(sm + 131328); // [16][32]

      if (tid < 320) ash[tid] = act_t[m0 * 10 + tid];
      {
        int row = tid >> 4, sg = tid & 15;
        const float4* xp = (const float4*)(xb + (size_t)(m0 + row) * 1024 + sg * 64);
        float s = 0.f, q = 0.f;
#pragma unroll
        for (int i = 0; i < 16; ++i) {
          float4 v = xp[i];
          s += v.x + v.y + v.z + v.w;
          q += v.x * v.x + v.y * v.y + v.z * v.z + v.w * v.w;
        }
#pragma unroll
        for (int o = 1; o < 16; o <<= 1) {
          s += __shfl_xor(s, o);
          q += __shfl_xor(q, o);
        }
        if (sg == 0) {
          float mu = s * (1.f / 1024.f);
          lmu[row] = mu;
          lrsd[row] = rsqrtf(q * (1.f / 1024.f) - mu * mu + LN_EPS);
        }
      }
      __syncthreads();

#define Z_STAGEA(BB, S) if (tid < 256) { \
    int row = tid >> 3, k8 = tid & 7; \
    const float* xp = xb + (size_t)(m0 + row) * 1024 + (S) * 64 + k8 * 8; \
    float mu = lmu[row], rs = lrsd[row]; \
    s8v v; \
    _Pragma("unroll") for (int e = 0; e < 8; ++e) { \
      int c = (S) * 64 + k8 * 8 + e; \
      float y = (xp[e] - mu) * rs * a.ln_post_s[c] + a.ln_post_b[c]; \
      y = y > 0.f ? y : expm1f(y); \
      v[e] = (short)f2bf(y); \
    } \
    *(s8v*)(AsB + (BB) * 4096 + row * 128 + ((k8 ^ (row & 7)) * 16)) = v; }

#define Z_STAGEB(BB, S) { \
    const u16* bsrc = a.postwP + (size_t)(S) * 8192; \
    glds16(bsrc + (w * 2) * 512 + lane * 8, BsB + (BB) * 16384 + w * 2048); \
    glds16(bsrc + (w * 2 + 1) * 512 + lane * 8, BsB + (BB) * 16384 + w * 2048 + 1024); }

      f4v acc0 = (f4v)(0.f), acc1 = (f4v)(0.f);
      Z_STAGEA(0, 0)
      Z_STAGEB(0, 0)
      int buf = 0;
      for (int s = 0; s < 16; ++s) {
        if (s + 1 < 16) {
          Z_STAGEA(buf ^ 1, s + 1)
          Z_STAGEB(buf ^ 1, s + 1)
          asm volatile("s_waitcnt vmcnt(2) lgkmcnt(0)" ::: "memory");
        } else {
          asm volatile("s_waitcnt vmcnt(0) lgkmcnt(0)" ::: "memory");
        }
        RAW_BAR();
#pragma unroll
        for (int kk = 0; kk < 2; ++kk) {
          int ch = kk * 4 + lk;
          int r0 = lr, r1 = 16 + lr;
          s8v a0 = *(const s8v*)(AsB + buf * 4096 + r0 * 128 + ((ch ^ (r0 & 7)) * 16));
          s8v a1 = *(const s8v*)(AsB + buf * 4096 + r1 * 128 + ((ch ^ (r1 & 7)) * 16));
          s8v b = *(const s8v*)(BsB + buf * 16384 + ch * 2048 + (w * 16 + lr) * 16);
          acc0 = MFMA16(a0, b, acc0, 0, 0, 0);
          acc1 = MFMA16(a1, b, acc1, 0, 0, 0);
        }
        __builtin_amdgcn_s_barrier();
        buf ^= 1;
      }
#undef Z_STAGEA
#undef Z_STAGEB

      {
        int colp = w * 16 + lr;
#pragma unroll
        for (int r = 0; r < 4; ++r) {
          int row0 = lk * 4 + r;
          float v0 = acc0[r] + a.post_b[colp];
          posts_t[(size_t)(m0 + row0) * 128 + colp] = v0;
          ps[row0 * 132 + colp] = v0;
          float v1 = acc1[r] + a.post_b[colp];
          posts_t[(size_t)(m0 + 16 + row0) * 128 + colp] = v1;
          ps[(16 + row0) * 132 + colp] = v1;
        }
      }
      __syncthreads();
#pragma unroll
      for (int q = 0; q < 4; ++q) {
        int e = q * 512 + tid;
        int row = e >> 6, j = e & 63;
        float mean = ps[row * 132 + j], sraw = ps[row * 132 + 64 + j];
        float sd = 2.f / (1.f + expf(-sraw)) + 0.1f;
        float z = mean + sd * noise_t[(m0 + row) * 64 + j];
        zout[(m0 + row) * 64 + j] = z;
        a.out_feat[(size_t)(t * 256 + m0 + row) * 2112 + 2048 + j] = z;
        *(u16*)(zblB + row * 128 + (((j >> 3) ^ (row & 7)) << 4) + (j & 7) * 2) =
            f2bf(z);
      }
      __syncthreads();

      // za a-part (cols 512..1023)
      {
        float accv[32];
#pragma unroll
        for (int r = 0; r < 32; ++r) accv[r] = 0.f;
#pragma unroll
        for (int k = 0; k < 10; ++k) {
          float wv = a.awT[k * 512 + tid];
#pragma unroll
          for (int r = 0; r < 32; ++r) accv[r] += ash[r * 10 + k] * wv;
        }
        int c = 512 + tid;
        int chs = c >> 3, cb = (c & 7) * 2;
#pragma unroll
        for (int r = 0; r < 32; ++r)
          *(u16*)(zal + r * 2048 + ((chs ^ (r & 7)) << 4) + cb) = f2bf(accv[r]);
      }
      // za z-part (cols 0..511): MFMA over 4 col-chunks of 128
      for (int c4 = 0; c4 < 4; ++c4) {
        glds16(a.zwP + c4 * 8192 + (w * 2) * 512 + lane * 8, BsB + w * 2048);
        glds16(a.zwP + c4 * 8192 + (w * 2 + 1) * 512 + lane * 8,
               BsB + w * 2048 + 1024);
        asm volatile("s_waitcnt vmcnt(0)" ::: "memory");
        RAW_BAR();
        f4v z0 = (f4v)(0.f), z1 = (f4v)(0.f);
#pragma unroll
        for (int kk = 0; kk < 2; ++kk) {
          int ch = kk * 4 + lk;
          int r0 = lr, r1 = 16 + lr;
          s8v a0 = *(const s8v*)(zblB + r0 * 128 + ((ch ^ (r0 & 7)) << 4));
          s8v a1 = *(const s8v*)(zblB + r1 * 128 + ((ch ^ (r1 & 7)) << 4));
          s8v b = *(const s8v*)(BsB + ch * 2048 + (w * 16 + lr) * 16);
          z0 = MFMA16(a0, b, z0, 0, 0, 0);
          z1 = MFMA16(a1, b, z1, 0, 0, 0);
        }
        int zcol = c4 * 128 + w * 16 + lr;
        int chz = zcol >> 3, cbz = (zcol & 7) * 2;
        float zbias = a.z_mlp_b[zcol];
#pragma unroll
        for (int r = 0; r < 4; ++r) {
          int ra = lk * 4 + r, rb = 16 + lk * 4 + r;
          *(u16*)(zal + ra * 2048 + ((chz ^ (ra & 7)) << 4) + cbz) =
              f2bf(z0[r] + zbias);
          *(u16*)(zal + rb * 2048 + ((chz ^ (rb & 7)) << 4) + cbz) =
              f2bf(z1[r] + zbias);
        }
        RAW_BAR();
      }
      __syncthreads();
      // za LN stats
      {
        int row = tid & 31, g = tid >> 5;
        float s = 0.f, q = 0.f;
#pragma unroll
        for (int jj = 0; jj < 8; ++jj) {
          int chunk = g * 8 + jj;
          s8v v = *(const s8v*)(zal + row * 2048 + ((chunk ^ (row & 7)) << 4));
#pragma unroll
          for (int e = 0; e < 8; ++e) {
            float x = bf2f((u16)v[e]);
            s += x;
            q += x * x;
          }
        }
        psum[g * 32 + row] = s;
        qsum[g * 32 + row] = q;
        __syncthreads();
        if (tid < 32) {
          float ss = 0.f, qq = 0.f;
#pragma unroll
          for (int gg = 0; gg < 16; ++gg) {
            ss += psum[gg * 32 + tid];
            qq += qsum[gg * 32 + tid];
          }
          float mu = ss * (1.f / 1024.f);
          zmu[tid] = mu;
          zrsd[tid] = rsqrtf(qq * (1.f / 1024.f) - mu * mu + LN_EPS);
        }
      }
      __syncthreads();
      // apply LN+ELU, write za
      {
        int row = tid >> 4, g = tid & 15;
        float mu = zmu[row], rs = zrsd[row];
        u16* dst = a.za + (size_t)(m0 + row) * 1024 + g * 64;
#pragma unroll
        for (int jj = 0; jj < 8; ++jj) {
          int chunk = g * 8 + jj;
          s8v v = *(const s8v*)(zal + row * 2048 + ((chunk ^ (row & 7)) << 4));
          s8v o;
#pragma unroll
          for (int e = 0; e < 8; ++e) {
            int c = chunk * 8 + e;
            float y = (bf2f((u16)v[e]) - mu) * rs * a.ln_za_s[c] + a.ln_za_b[c];
            y = y > 0.f ? y : expm1f(y);
            o[e] = (short)f2bf(y);
          }
          *(s8v*)(dst + jj * 8) = o;
        }
      }
    }
    gbar(a.bars, t * 3 + 2, 128);
  }
}

// ---------------- batched 8-wave GEMM (embed / prior phases) ----------------
// XYSWAP: grid=(Nt, Mt) so consecutive blocks share A rows (L2 reuse).
template <bool AF32, bool OUTBF16, bool XYSWAP>
__global__ __launch_bounds__(512) void k_gemm8(
    const void* __restrict__ Av, int lda, const u16* __restrict__ Bw, int ldb,
    int nstage, float* __restrict__ Cf, u16* __restrict__ Cb, int ldc,
    const float* __restrict__ bias) {
  const int bx = XYSWAP ? blockIdx.y : blockIdx.x;
  const int by = XYSWAP ? blockIdx.x : blockIdx.y;
  const int tid = threadIdx.x;
  const int m0 = bx * 64;
  const int n0 = by * 128;
  __shared__ __align__(16) u16 As[64][72];
  __shared__ __align__(16) u16 Bs[128][72];
  const int lane = tid & 63;
  const int w = tid >> 6;
  const int wr = w >> 2;
  const int wc = w & 3;
  const int lr = lane & 15;
  const int lk = lane >> 4;

  f4v acc[2][2];
#pragma unroll
  for (int m = 0; m < 2; ++m)
#pragma unroll
    for (int n = 0; n < 2; ++n) acc[m][n] = (f4v)(0.0f);

  for (int s = 0; s < nstage; ++s) {
    const int k0 = s << 6;
    {
      int row = tid >> 3, k8 = (tid & 7) << 3;
      if (AF32) {
        const float* ap = (const float*)Av + (size_t)(m0 + row) * lda + k0 + k8;
        float4 f0 = *(const float4*)ap;
        float4 f1 = *(const float4*)(ap + 4);
        s8v v;
        v[0] = (short)f2bf(f0.x); v[1] = (short)f2bf(f0.y);
        v[2] = (short)f2bf(f0.z); v[3] = (short)f2bf(f0.w);
        v[4] = (short)f2bf(f1.x); v[5] = (short)f2bf(f1.y);
        v[6] = (short)f2bf(f1.z); v[7] = (short)f2bf(f1.w);
        *(s8v*)&As[row][k8] = v;
      } else {
        *(s8v*)&As[row][k8] =
            *(const s8v*)((const u16*)Av + (size_t)(m0 + row) * lda + k0 + k8);
      }
    }
#pragma unroll
    for (int it = 0; it < 2; ++it) {
      int c = tid + it * 512;
      int row = c >> 3, k8 = (c & 7) << 3;
      *(s8v*)&Bs[row][k8] = *(const s8v*)(Bw + (size_t)(n0 + row) * ldb + k0 + k8);
    }
    __syncthreads();
#pragma unroll
    for (int kk = 0; kk < 2; ++kk) {
      const int koff = kk * 32 + lk * 8;
      s8v a[2], b[2];
      a[0] = *(const s8v*)&As[wr * 32 + lr][koff];
      a[1] = *(const s8v*)&As[wr * 32 + 16 + lr][koff];
      b[0] = *(const s8v*)&Bs[wc * 32 + lr][koff];
      b[1] = *(const s8v*)&Bs[wc * 32 + 16 + lr][koff];
#pragma unroll
      for (int m = 0; m < 2; ++m)
#pragma unroll
        for (int n = 0; n < 2; ++n)
          acc[m][n] = MFMA16(a[m], b[n], acc[m][n], 0, 0, 0);
    }
    __syncthreads();
  }
#pragma unroll
  for (int m = 0; m < 2; ++m) {
#pragma unroll
    for (int n = 0; n < 2; ++n) {
#pragma unroll
      for (int r = 0; r < 4; ++r) {
        int row = m0 + wr * 32 + m * 16 + lk * 4 + r;
        int col = n0 + wc * 32 + n * 16 + lr;
        float v = acc[m][n][r];
        if (bias) v += bias[col];
        if (OUTBF16)
          Cb[(size_t)row * ldc + col] = f2bf(v);
        else
          Cf[(size_t)row * ldc + col] = v;
      }
    }
  }
}

// ---------------- LN + ELU (rows of 1024), bf16 in/out ----------------
__global__ __launch_bounds__(256) void k_lnelu(const u16* __restrict__ xsrc,
                                               const float* __restrict__ s,
                                               const float* __restrict__ bb,
                                               u16* __restrict__ out) {
  int row = blockIdx.x, tid = threadIdx.x;
  __shared__ float red[256];
  float v[4];
#pragma unroll
  for (int i = 0; i < 4; ++i) {
    size_t idx = (size_t)row * 1024 + tid + i * 256;
    v[i] = bf2f(xsrc[idx]);
  }
  float sm = v[0] + v[1] + v[2] + v[3];
  red[tid] = sm;
  __syncthreads();
  for (int o = 128; o > 0; o >>= 1) {
    if (tid < o) red[tid] += red[tid + o];
    __syncthreads();
  }
  float mu = red[0] * (1.0f / 1024.0f);
  __syncthreads();
  float q = 0.f;
#pragma unroll
  for (int i = 0; i < 4; ++i) {
    float d = v[i] - mu;
    q += d * d;
  }
  red[tid] = q;
  __syncthreads();
  for (int o = 128; o > 0; o >>= 1) {
    if (tid < o) red[tid] += red[tid + o];
    __syncthreads();
  }
  float rs = rsqrtf(red[0] * (1.0f / 1024.0f) + LN_EPS);
#pragma unroll
  for (int i = 0; i < 4; ++i) {
    int c = tid + i * 256;
    float y = (v[i] - mu) * rs * s[c] + bb[c];
    y = y > 0.f ? y : expm1f(y);
    out[(size_t)row * 1024 + c] = f2bf(y);
  }
}

extern "C" void kernel_launch(void* const* d_in, const int* in_sizes, int n_in,
                              void* d_out, int out_size, void* d_ws,
                              size_t ws_size, hipStream_t stream) {
  const float* embeds = (const float*)d_in[0];
  const float* actions = (const float*)d_in[1];
  const float* h_t = (const float*)d_in[2];
  const float* z_t = (const float*)d_in[3];
  const float* noise = (const float*)d_in[4];
  const float* z_mlp_w = (const float*)d_in[5];
  const float* z_mlp_b = (const float*)d_in[6];
  const float* a_mlp_w = (const float*)d_in[7];
  const float* ln_za_s = (const float*)d_in[8];
  const float* ln_za_b = (const float*)d_in[9];
  const float* gru_wih = (const float*)d_in[10];
  const float* gru_whh = (const float*)d_in[11];
  const float* gru_bih = (const float*)d_in[12];
  const float* gru_bhh = (const float*)d_in[13];
  const float* post_h_w = (const float*)d_in[14];
  const float* post_h_b = (const float*)d_in[15];
  const float* post_e_w = (const float*)d_in[16];
  const float* post_e_b = (const float*)d_in[17];
  const float* ln_post_s = (const float*)d_in[18];
  const float* ln_post_b = (const float*)d_in[19];
  const float* post_w = (const float*)d_in[20];
  const float* post_b = (const float*)d_in[21];
  const float* prior_h_w = (const float*)d_in[22];
  const float* prior_h_b = (const float*)d_in[23];
  const float* ln_prior_s = (const float*)d_in[24];
  const float* ln_prior_b = (const float*)d_in[25];
  const float* prior_w = (const float*)d_in[26];
  const float* prior_b = (const float*)d_in[27];

  float* out = (float*)d_out;
  float* out_priors = out;           // [64,256,128]
  float* out_posts = out + 2097152;  // [64,256,128]
  float* out_z = out + 4194304;      // [64,256,64]
  float* out_feat = out + 5242880;   // [64,256,2112]

  char* ws = (char*)d_ws;
  size_t off = 0;
  auto alloc = [&](size_t bytes) {
    char* p = ws + off;
    off += (bytes + 255) & ~(size_t)255;
    return p;
  };
  char* regW = alloc((size_t)32 * 48 * 12288 * 2);  // 37.75 MB
  u16* wt = (u16*)regW;
  u16* prx_b = (u16*)regW;
  u16* posthP = (u16*)alloc((size_t)1024 * 2048 * 2);
  u16* postwP = (u16*)alloc((size_t)128 * 1024 * 2);
  u16* poste_b = (u16*)alloc((size_t)1024 * 1536 * 2);
  u16* priorh_b = (u16*)alloc((size_t)1024 * 2048 * 2);
  u16* priorw_b = (u16*)alloc((size_t)128 * 1024 * 2);
  u16* zwP = (u16*)alloc((size_t)512 * 64 * 2);
  float* awT = (float*)alloc((size_t)10 * 512 * 4);
  u16* hcat0 = (u16*)alloc((size_t)256 * 2048 * 2);
  u16* hcat1 = (u16*)alloc((size_t)256 * 2048 * 2);
  float* hf0 = (float*)alloc((size_t)256 * 2048 * 4);
  float* hf1 = (float*)alloc((size_t)256 * 2048 * 4);
  float* xbuf = (float*)alloc((size_t)256 * 1024 * 4);
  u16* za = (u16*)alloc((size_t)256 * 1024 * 2);
  unsigned* bars = (unsigned*)alloc((size_t)192 * 32 * 4);
  char* regU = alloc((size_t)16384 * 1024 * 2);  // 33.55 MB
  u16* e_part = (u16*)regU;
  u16* p_pr = (u16*)regU;

  // ---- packing + conversions + h init + za(t=0) + barrier zero ----
  k_zero<<<24, 256, 0, stream>>>(bars, 192 * 32);
  k_packgru<<<9216, 256, 0, stream>>>(gru_wih, gru_whh, wt);
  k_packB<<<1024, 256, 0, stream>>>(post_h_w, posthP, 2048, 64, 262144);
  k_packB<<<64, 256, 0, stream>>>(post_w, postwP, 1024, 128, 16384);
  k_packB<<<16, 256, 0, stream>>>(z_mlp_w, zwP, 64, 128, 4096);
  k_trA<<<20, 256, 0, stream>>>(a_mlp_w, awT);
  k_cvt<<<512, 256, 0, stream>>>(post_e_w, poste_b, 1024 * 1536);
  k_cvt<<<512, 256, 0, stream>>>(prior_h_w, priorh_b, 1024 * 2048);
  k_cvt<<<64, 256, 0, stream>>>(prior_w, priorw_b, 128 * 1024);
  k_hinit<<<2048, 256, 0, stream>>>(h_t, hf0, hcat0);
  k_za0<<<256, 256, 0, stream>>>(z_t, actions, z_mlp_w, z_mlp_b, a_mlp_w,
                                 ln_za_s, ln_za_b, za);

  // ---- batched embed projection (XYSWAP grid for A-row L2 reuse) ----
  k_gemm8<true, true, true><<<dim3(8, 256), 512, 0, stream>>>(
      embeds, 1536, poste_b, 1536, 24, nullptr, e_part, 1024, post_e_b);

  // ---- persistent cooperative scan (one launch, custom slot barriers) ----
  ScanArgs sa;
  sa.wt = wt;
  sa.bih = gru_bih;
  sa.bhh = gru_bhh;
  sa.hcat0 = hcat0;
  sa.hcat1 = hcat1;
  sa.hf0 = hf0;
  sa.hf1 = hf1;
  sa.za = za;
  sa.posthP = posthP;
  sa.post_h_b = post_h_b;
  sa.e_part = e_part;
  sa.xbuf = xbuf;
  sa.postwP = postwP;
  sa.ln_post_s = ln_post_s;
  sa.ln_post_b = ln_post_b;
  sa.post_b = post_b;
  sa.out_posts = out_posts;
  sa.noise = noise;
  sa.out_z = out_z;
  sa.out_feat = out_feat;
  sa.zwP = zwP;
  sa.z_mlp_b = z_mlp_b;
  sa.awT = awT;
  sa.actions = actions;
  sa.ln_za_s = ln_za_s;
  sa.ln_za_b = ln_za_b;
  sa.bars = bars;
  void* kargs[] = {(void*)&sa};
  hipLaunchCooperativeKernel((const void*)k_scan, dim3(128), dim3(512), kargs,
                             0, stream);

  // ---- batched prior head (wt/e_part dead; reuse regions) ----
  k_gemm8<true, true, true><<<dim3(8, 256), 512, 0, stream>>>(
      out_feat, 2112, priorh_b, 2048, 32, nullptr, prx_b, 1024, prior_h_b);
  k_lnelu<<<16384, 256, 0, stream>>>(prx_b, ln_prior_s, ln_prior_b, p_pr);
  k_gemm8<false, false, false><<<dim3(256, 1), 512, 0, stream>>>(
      p_pr, 1024, priorw_b, 1024, 16, out_priors, nullptr, 128, prior_b);
}